// Round 4
// baseline (108.756 us; speedup 1.0000x reference)
//
#include <hip/hip_runtime.h>
#include <cmath>

// pa_lif: T=8, tau=0.25, thresh=0.5. Per-column recurrence (absmax 0.0 R2-R5):
//   w[i]   = 0.25*x[i] + 0.75*w[i-1]                      (W_CONST @ x as IIR)
//   p1[i]  = sigmoid(0.5 - 0.5*(0.25*x[i] + w[i]))
//   pre[i] = 0.25*(x[i] + S[i]) - 0.5 ;  out[i] = pre[i] > 0
//   S[i+1] = 0.25*p1[i]*(S[i] + x[i]) ;  S[0] = 0
//
// R6: kill the ot[8] staging array (32 VGPRs). Previous kernel held xr[8]
// (live for the refine branch) AND ot[8] simultaneously ~= 88 VGPR -> only
// ~5 waves/SIMD; streaming-load latency hiding wants 8. New structure:
//   pass1: store-free recurrence computing only mn (w/S chains, no selects)
//   branch fast: re-run recurrence from the still-live xr[], store each row
//                as produced (NT) -- still exactly ONE store site per address
//   branch refine (~0.4%/thread, ~23% of waves): fp64 from xr[], unchanged
// CSE trap: pass2's expressions are identical to pass1's; GVN would reuse
// the pass1 values and resurrect ot[] as carried registers. Each xr element
// is laundered through an empty asm ("+v") so every pass2 value is formally
// new (rule-17 mechanism, zero instructions). Extra ~800 cyc/wave recompute
// is hidden under the ~16-21 us memory floor (R0: FETCH 33 MB L3-assisted +
// WRITE 67 MB).
//
// Fast-path precision (R5, verified absmax 0.0): __expf + v_rcp give |pre|
// error <~3e-7; REFINE_THRESH 5e-6 keeps 15-20x margin, boundary lanes get
// exact fp64 regardless. STEP math unchanged bit-for-bit from R5.
// Determinism: fast-store and refine-store are exclusive branches; every
// output address is written by exactly one store site per launch.

#define TT 8
#define REFINE_THRESH 5e-6f

// native vector type: __builtin_nontemporal_store requires a real vector,
// not HIP's float4 class
typedef float vfloat4 __attribute__((ext_vector_type(4)));

// break value-numbering between pass1 and pass2 (no code emitted)
#define LAUNDER(v) asm volatile("" : "+v"(v))

// pass1 step: recurrence + min-|pre| tracking only (no output select)
#define STEP32M(xik, w, S)                                    \
    {                                                         \
        float xk_ = (xik);                                    \
        w = fmaf(0.75f, w, 0.25f * xk_);                      \
        float arg_ = fmaf(-0.5f, fmaf(0.25f, xk_, w), 0.5f);  \
        float t_ = __expf(-arg_);                             \
        float p1_ = __builtin_amdgcn_rcpf(1.0f + t_);         \
        float sx_ = S + xk_;                                  \
        float pre_ = fmaf(0.25f, sx_, -0.5f);                 \
        float a_ = fabsf(pre_);                               \
        mn = (a_ < mn) ? a_ : mn;                             \
        S = 0.25f * p1_ * sx_;                                \
    }

// pass2 step: recurrence + output select (no mn tracking)
#define STEP32S(xik, w, S, o)                                 \
    {                                                         \
        float xk_ = (xik);                                    \
        w = fmaf(0.75f, w, 0.25f * xk_);                      \
        float arg_ = fmaf(-0.5f, fmaf(0.25f, xk_, w), 0.5f);  \
        float t_ = __expf(-arg_);                             \
        float p1_ = __builtin_amdgcn_rcpf(1.0f + t_);         \
        float sx_ = S + xk_;                                  \
        float pre_ = fmaf(0.25f, sx_, -0.5f);                 \
        o = (pre_ > 0.0f) ? 1.0f : 0.0f;                      \
        S = 0.25f * p1_ * sx_;                                \
    }

// one fp64 recurrence step (rare path; matches R2's refine bit-for-bit).
#define STEP64(xif, wd, Sd, o)                                \
    {                                                         \
        double xd_ = (double)(xif);                           \
        wd = 0.25 * xd_ + 0.75 * wd;                          \
        double arg_ = 0.5 - 0.5 * (0.25 * xd_ + wd);          \
        double p1_ = 1.0 / (1.0 + exp(-arg_));                \
        double pre_ = 0.25 * (xd_ + Sd) - 0.5;                \
        o = (pre_ > 0.0) ? 1.0f : 0.0f;                       \
        Sd = 0.25 * p1_ * (Sd + xd_);                         \
    }

__global__ __launch_bounds__(256)
void pa_lif_kernel(const float* __restrict__ x, float* __restrict__ out, int dim4) {
    int tid = blockIdx.x * blockDim.x + threadIdx.x;
    if (tid >= dim4) return;

    const float4* __restrict__ xv = (const float4*)x;
    float4* __restrict__ ov = (float4*)out;
    vfloat4* __restrict__ onv = (vfloat4*)out;

    // stage all 8 rows up-front: 8 independent global_load_dwordx4 in flight
    // (R3 win: progressive vmcnt consumption instead of 8 serial round-trips)
    float4 xr[TT];
#pragma unroll
    for (int i = 0; i < TT; ++i)
        xr[i] = xv[(size_t)i * dim4 + tid];

    float w0 = 0.f, w1 = 0.f, w2 = 0.f, w3 = 0.f;
    float S0 = 0.f, S1 = 0.f, S2 = 0.f, S3 = 0.f;
    float mn = 1e30f;

    // pass1: min-|pre| only -- no outputs staged, nothing but mn survives
#pragma unroll
    for (int i = 0; i < TT; ++i) {
        STEP32M(xr[i].x, w0, S0);
        STEP32M(xr[i].y, w1, S1);
        STEP32M(xr[i].z, w2, S2);
        STEP32M(xr[i].w, w3, S3);
    }

    if (__builtin_expect(mn >= REFINE_THRESH, 1)) {
        // pass2: recompute from live xr[] and store each row as produced.
        // LAUNDER breaks CSE with pass1 so no 32-reg output array is carried.
        w0 = w1 = w2 = w3 = 0.f;
        S0 = S1 = S2 = S3 = 0.f;
#pragma unroll
        for (int i = 0; i < TT; ++i) {
            float xx = xr[i].x, xy = xr[i].y, xz = xr[i].z, xw = xr[i].w;
            LAUNDER(xx); LAUNDER(xy); LAUNDER(xz); LAUNDER(xw);
            vfloat4 o;
            STEP32S(xx, w0, S0, o.x);
            STEP32S(xy, w1, S1, o.y);
            STEP32S(xz, w2, S2, o.z);
            STEP32S(xw, w3, S3, o.w);
            // write-once stream: bypass L2 with nontemporal 16B stores
            __builtin_nontemporal_store(o, &onv[(size_t)i * dim4 + tid]);
        }
    } else {
        // rare-lane fp64 recompute from the staged registers (no reloads).
        // Fully unrolled: xr[] indices stay compile-time constants so the
        // array lives in VGPRs, not scratch (runtime indexing would spill).
        double wd0 = 0, wd1 = 0, wd2 = 0, wd3 = 0;
        double Sd0 = 0, Sd1 = 0, Sd2 = 0, Sd3 = 0;
#pragma unroll
        for (int i = 0; i < TT; ++i) {
            float4 xi = xr[i];
            float4 o;
            STEP64(xi.x, wd0, Sd0, o.x);
            STEP64(xi.y, wd1, Sd1, o.y);
            STEP64(xi.z, wd2, Sd2, o.z);
            STEP64(xi.w, wd3, Sd3, o.w);
            ov[(size_t)i * dim4 + tid] = o;
        }
    }
}

extern "C" void kernel_launch(void* const* d_in, const int* in_sizes, int n_in,
                              void* d_out, int out_size, void* d_ws, size_t ws_size,
                              hipStream_t stream) {
    (void)n_in; (void)out_size; (void)d_ws; (void)ws_size;
    const float* x = (const float*)d_in[0];
    float* out = (float*)d_out;
    int total = in_sizes[0];        // T * dim = 16,777,216
    int dim = total / TT;           // 2,097,152 columns
    int dim4 = dim / 4;             // 524,288 threads (float4 per thread)
    int block = 256;
    int grid = (dim4 + block - 1) / block;
    pa_lif_kernel<<<grid, block, 0, stream>>>(x, out, dim4);
}

// Round 5
// 106.814 us; speedup vs baseline: 1.0182x; 1.0182x over previous
//
#include <hip/hip_runtime.h>
#include <cmath>

// pa_lif: T=8, tau=0.25, thresh=0.5. Per-column recurrence (absmax 0.0 R2-R7):
//   w[i]   = 0.25*x[i] + 0.75*w[i-1]                      (W_CONST @ x as IIR)
//   p1[i]  = sigmoid(0.5 - 0.5*(0.25*x[i] + w[i]))
//   pre[i] = 0.25*(x[i] + S[i]) - 0.5 ;  out[i] = pre[i] > 0
//   S[i+1] = 0.25*p1[i]*(S[i] + x[i]) ;  S[0] = 0
//
// R7: R4's two-pass recompute regressed (106.7 -> 108.8): the pass2 VALU
// (~800 cyc for 77% of waves) was NOT hidden -- bench responds ~1:1 to
// kernel VALU beyond the ~16 us memory floor. Revert to R3's single-pass
// structure, but fix its register problem differently: ot[8] held 32
// BOOLEANS in 32 VGPRs. Pack them into one 32-bit obits register during
// the compute pass (1 bit/step), unpack in the fast branch with bfe+cvt
// (exact 0.0f/1.0f). Net: -31 VGPR (~88 -> ~60, 5 -> 8 waves/SIMD) for
// +~96 VALU (~4%) -- more TLP to hide the 8-deep load latency and the
// rare-wave fp64 tax, with NO recompute.
//
// Fast-path precision (R5, verified absmax 0.0): __expf + v_rcp give |pre|
// error <~3e-7; REFINE_THRESH 5e-6 keeps 15-20x margin; refine rate
// ~0.4%/thread -> P(wave refines) ~23%. pre_ computation, refined set, and
// both store paths' arithmetic are bit-identical to the verified R3/R5
// kernels -- only the boolean representation changed.
// Determinism rule (round-1 lesson): every output address is written by
// EXACTLY ONE store site per launch -- fast-store and refine-store are
// exclusive branches, no overwrites.

#define TT 8
#define REFINE_THRESH 5e-6f

// native vector type: __builtin_nontemporal_store requires a real vector,
// not HIP's float4 class
typedef float vfloat4 __attribute__((ext_vector_type(4)));

// one fast fp32 recurrence step; packs the spike bit into obits[bit]
#define STEP32(xik, w, S, bit)                                \
    {                                                         \
        float xk_ = (xik);                                    \
        w = fmaf(0.75f, w, 0.25f * xk_);                      \
        float arg_ = fmaf(-0.5f, fmaf(0.25f, xk_, w), 0.5f);  \
        float t_ = __expf(-arg_);                             \
        float p1_ = __builtin_amdgcn_rcpf(1.0f + t_);         \
        float sx_ = S + xk_;                                  \
        float pre_ = fmaf(0.25f, sx_, -0.5f);                 \
        obits |= (pre_ > 0.0f) ? (1u << (bit)) : 0u;          \
        float a_ = fabsf(pre_);                               \
        mn = (a_ < mn) ? a_ : mn;                             \
        S = 0.25f * p1_ * sx_;                                \
    }

// one fp64 recurrence step (rare path; matches R2's refine bit-for-bit).
#define STEP64(xif, wd, Sd, o)                                \
    {                                                         \
        double xd_ = (double)(xif);                           \
        wd = 0.25 * xd_ + 0.75 * wd;                          \
        double arg_ = 0.5 - 0.5 * (0.25 * xd_ + wd);          \
        double p1_ = 1.0 / (1.0 + exp(-arg_));                \
        double pre_ = 0.25 * (xd_ + Sd) - 0.5;                \
        o = (pre_ > 0.0) ? 1.0f : 0.0f;                       \
        Sd = 0.25 * p1_ * (Sd + xd_);                         \
    }

__global__ __launch_bounds__(256)
void pa_lif_kernel(const float* __restrict__ x, float* __restrict__ out, int dim4) {
    int tid = blockIdx.x * blockDim.x + threadIdx.x;
    if (tid >= dim4) return;

    const float4* __restrict__ xv = (const float4*)x;
    float4* __restrict__ ov = (float4*)out;
    vfloat4* __restrict__ onv = (vfloat4*)out;

    // stage all 8 rows up-front: 8 independent global_load_dwordx4 issue
    // back-to-back, consumed with progressive vmcnt waits (MLP = 128 B/thread)
    float4 xr[TT];
#pragma unroll
    for (int i = 0; i < TT; ++i)
        xr[i] = xv[(size_t)i * dim4 + tid];

    float w0 = 0.f, w1 = 0.f, w2 = 0.f, w3 = 0.f;
    float S0 = 0.f, S1 = 0.f, S2 = 0.f, S3 = 0.f;
    float mn = 1e30f;
    unsigned obits = 0u;   // 32 spike booleans, 1 bit each (bit = 4*i + lane4)

#pragma unroll
    for (int i = 0; i < TT; ++i) {
        STEP32(xr[i].x, w0, S0, 4 * i + 0);
        STEP32(xr[i].y, w1, S1, 4 * i + 1);
        STEP32(xr[i].z, w2, S2, 4 * i + 2);
        STEP32(xr[i].w, w3, S3, 4 * i + 3);
    }

    if (__builtin_expect(mn >= REFINE_THRESH, 1)) {
        // unpack bits to exact 0.0f/1.0f (v_bfe_u32 + v_cvt_f32_u32 each)
        // write-once stream: bypass L2 with nontemporal 16B stores
#pragma unroll
        for (int i = 0; i < TT; ++i) {
            vfloat4 o;
            o.x = (float)((obits >> (4 * i + 0)) & 1u);
            o.y = (float)((obits >> (4 * i + 1)) & 1u);
            o.z = (float)((obits >> (4 * i + 2)) & 1u);
            o.w = (float)((obits >> (4 * i + 3)) & 1u);
            __builtin_nontemporal_store(o, &onv[(size_t)i * dim4 + tid]);
        }
    } else {
        // rare-lane fp64 recompute from the staged registers (no reloads).
        // Fully unrolled: xr[] indices stay compile-time constants so the
        // array lives in VGPRs, not scratch (runtime indexing would spill).
        double wd0 = 0, wd1 = 0, wd2 = 0, wd3 = 0;
        double Sd0 = 0, Sd1 = 0, Sd2 = 0, Sd3 = 0;
#pragma unroll
        for (int i = 0; i < TT; ++i) {
            float4 xi = xr[i];
            float4 o;
            STEP64(xi.x, wd0, Sd0, o.x);
            STEP64(xi.y, wd1, Sd1, o.y);
            STEP64(xi.z, wd2, Sd2, o.z);
            STEP64(xi.w, wd3, Sd3, o.w);
            ov[(size_t)i * dim4 + tid] = o;
        }
    }
}

extern "C" void kernel_launch(void* const* d_in, const int* in_sizes, int n_in,
                              void* d_out, int out_size, void* d_ws, size_t ws_size,
                              hipStream_t stream) {
    (void)n_in; (void)out_size; (void)d_ws; (void)ws_size;
    const float* x = (const float*)d_in[0];
    float* out = (float*)d_out;
    int total = in_sizes[0];        // T * dim = 16,777,216
    int dim = total / TT;           // 2,097,152 columns
    int dim4 = dim / 4;             // 524,288 threads (float4 per thread)
    int block = 256;
    int grid = (dim4 + block - 1) / block;
    pa_lif_kernel<<<grid, block, 0, stream>>>(x, out, dim4);
}